// Round 5
// baseline (477.422 us; speedup 1.0000x reference)
//
#include <hip/hip_runtime.h>

// 3x3 SAME conv + bias + ReLU, N=32, Cin=Cout=256, H=W=56, fp32 in/out.
// v5: implicit-GEMM bf16 MFMA (16x16x32).
//  - A (weights): registers, direct from L2-resident repacked array,
//    software-pipelined 1 tap ahead. No LDS for A.
//  - B (x patch): 6x60px x 32ch bf16 patch in LDS, double-buffered;
//    next chunk staged DURING current chunk's 9 barrier-free taps.
//    One __syncthreads per chunk.
//  - 256 thr / 4 waves, wave tile 64co x 112px (4m x 7n), co-split x2,
//    896 blocks -> 2 blocks/CU.

typedef __attribute__((ext_vector_type(8))) short short8;
typedef __attribute__((ext_vector_type(4))) float f32x4;

#define CIN   256
#define HWS   3136      // 56*56
#define KTOT  2304      // CIN*9
#define WROWB 4608      // KTOT*2 bytes per weight row
#define PBUF  23040u    // 360 granules * 64B

__device__ __forceinline__ unsigned short f2bf(float f) {
  unsigned u = __builtin_bit_cast(unsigned, f);
  return (unsigned short)((u + 0x7fffu + ((u >> 16) & 1u)) >> 16);  // RNE
}

// Repack weights OIHW fp32 -> bf16 [co][tap*256+ci]
__global__ void wcvt_kernel(const float* __restrict__ w, unsigned short* __restrict__ wb) {
  int o = blockIdx.x * 256 + threadIdx.x;
  int co = o / KTOT;
  int rr = o - co * KTOT;
  int tap = rr >> 8;
  int ci = rr & 255;
  wb[o] = f2bf(w[co * KTOT + ci * 9 + tap]);
}

__global__ __launch_bounds__(256, 2) void conv_kernel(
    const float* __restrict__ x, const unsigned char* __restrict__ wb,
    const float* __restrict__ bias, float* __restrict__ out) {
  __shared__ __align__(16) unsigned char smem[2 * PBUF];

  const int bid   = blockIdx.x;
  const int sw    = (bid & 7) * 112 + (bid >> 3);  // XCD-chunked (896=8*112)
  const int co0   = (sw & 1) * 128;
  const int pt    = sw >> 1;                       // 0..447
  const int n_img = pt / 14;
  const int trow  = pt - n_img * 14;               // 4-row band
  const int ph0   = trow * 4;

  const int t    = threadIdx.x;
  const int lane = t & 63;
  const int wave = t >> 6;    // 0..3
  const int wm   = wave & 1;  // co 64-half of this block's 128
  const int wn   = wave >> 1; // px 112-half
  const int rl   = lane & 15;
  const int kq   = lane >> 4;

  const float* xn = x + (size_t)n_img * (CIN * HWS);

  // A fragment base pointers (per-lane, direct global)
  const unsigned char* aBase[4];
#pragma unroll
  for (int mi = 0; mi < 4; ++mi)
    aBase[mi] = wb + (size_t)(co0 + wm * 64 + mi * 16 + rl) * WROWB + kq * 16;

  // B pixel-granule bases (patch coords, rows padded to 60)
  int pb[7];
#pragma unroll
  for (int ni = 0; ni < 7; ++ni) {
    int px = wn * 112 + ni * 16 + rl;
    int pr = px / 56;
    pb[ni] = pr * 60 + (px - pr * 56);
  }

  f32x4 acc[4][7];
  const f32x4 zero4 = {0.f, 0.f, 0.f, 0.f};
#pragma unroll
  for (int mi = 0; mi < 4; ++mi)
#pragma unroll
    for (int ni = 0; ni < 7; ++ni) acc[mi][ni] = zero4;

  short8 areg[2][4];

  // ---- one staging sub-iteration (si 0..6) for chunk tc into buffer tb ----
  auto stageIter = [&](int si, int tc, unsigned tb) {
    if (si < 6) {
      const int tid = si * 256 + t;
      if (tid < 1344) {                       // 6 rows * 14 groups * 16 chpairs
        const int r   = tid / 224;
        const int rem = tid - r * 224;
        const int g   = rem >> 4;             // float4 group (x cols 4g..4g+3)
        const int cp  = rem & 15;             // channel pair
        const int xr  = ph0 + r - 1;
        const bool valid = (unsigned)xr < 56u;
        const float* s0 = xn + (size_t)(tc * 32 + cp * 2) * HWS
                             + (valid ? xr * 56 + g * 4 : 0);
        f32x4 fa = *(const f32x4*)s0;
        f32x4 fb = *(const f32x4*)(s0 + HWS);
        if (!valid) { fa = zero4; fb = zero4; }
#pragma unroll
        for (int i = 0; i < 4; ++i) {
          unsigned u = (unsigned)f2bf(fa[i]) | ((unsigned)f2bf(fb[i]) << 16);
          const int pp = r * 60 + g * 4 + 1 + i;   // patch col = x col + 1
          *(unsigned*)(smem + tb + pp * 64 +
                       (((unsigned)(cp * 4)) ^ (((unsigned)(pp >> 1) & 3u) << 4))) = u;
        }
      }
    } else {
      if (t < 192) {                          // zero pad cols 0 and 57, all 6 rows
        const int r   = t >> 5;
        const int rem = t & 31;
        const int pc  = (rem >> 4) ? 57 : 0;
        const int cp  = rem & 15;
        const int pp  = r * 60 + pc;
        *(unsigned*)(smem + tb + pp * 64 +
                     (((unsigned)(cp * 4)) ^ (((unsigned)(pp >> 1) & 3u) << 4))) = 0u;
      }
    }
  };

  auto loadA = [&](int chunk, int tap, short8* dst) {
    const int off = tap * 512 + chunk * 64;
#pragma unroll
    for (int mi = 0; mi < 4; ++mi)
      dst[mi] = *(const short8*)(aBase[mi] + off);
  };

  // ---- prologue: A(chunk0,tap0) + stage chunk0 -> buf0 ----
  loadA(0, 0, areg[0]);
#pragma unroll
  for (int si = 0; si < 7; ++si) stageIter(si, 0, 0u);
  __syncthreads();

  // ---- main: chunk pairs, 18 barrier-free-ish taps unrolled ----
  for (int cq = 0; cq < 8; cq += 2) {
#pragma unroll
    for (int sub = 0; sub < 18; ++sub) {
      const int tap = (sub >= 9) ? sub - 9 : sub;
      const unsigned pbase = (sub >= 9) ? PBUF : 0u;

      // prefetch next tap's A fragments
      if (sub < 17) {
        const int s1 = sub + 1;
        const int nc = cq + ((s1 >= 9) ? 1 : 0);
        const int nt = (s1 >= 9) ? s1 - 9 : s1;
        loadA(nc, nt, areg[s1 & 1]);
      } else if (cq < 6) {
        loadA(cq + 2, 0, areg[0]);
      }

      // staging of the next chunk, spread over taps 0..6
      if (tap < 7) {
        if (sub < 9) {
          stageIter(tap, cq + 1, PBUF);
        } else if (cq + 2 < 8) {
          stageIter(tap, cq + 2, 0u);
        }
      }

      // compute this tap: 7 ds_read_b128 + 28 MFMA
      {
        const int kh = tap / 3;
        const int kw = tap - kh * 3;
        short8 b[7];
#pragma unroll
        for (int ni = 0; ni < 7; ++ni) {
          const int pp = pb[ni] + kh * 60 + kw;
          b[ni] = *(const short8*)(smem + pbase + (unsigned)pp * 64 +
                   (((unsigned)(kq * 16)) ^ (((unsigned)(pp >> 1) & 3u) << 4)));
        }
#pragma unroll
        for (int mi = 0; mi < 4; ++mi)
#pragma unroll
          for (int ni = 0; ni < 7; ++ni)
            acc[mi][ni] = __builtin_amdgcn_mfma_f32_16x16x32_bf16(
                areg[sub & 1][mi], b[ni], acc[mi][ni], 0, 0, 0);
      }

      if (sub == 8 || (sub == 17 && cq < 6)) __syncthreads();
    }
  }

  // ---- epilogue: bias + ReLU. C/D: col=lane&15, row=(lane>>4)*4+j ----
  {
    float br[4][4];
#pragma unroll
    for (int mi = 0; mi < 4; ++mi)
#pragma unroll
      for (int j = 0; j < 4; ++j)
        br[mi][j] = bias[co0 + wm * 64 + mi * 16 + kq * 4 + j];

    float* outn = out + (size_t)n_img * (CIN * HWS);
#pragma unroll
    for (int mi = 0; mi < 4; ++mi) {
      const int row = co0 + wm * 64 + mi * 16 + kq * 4;
#pragma unroll
      for (int ni = 0; ni < 7; ++ni) {
        const int col = trow * 224 + wn * 112 + ni * 16 + rl;
        float* po = outn + (size_t)row * HWS + col;
#pragma unroll
        for (int j = 0; j < 4; ++j) {
          float v = acc[mi][ni][j] + br[mi][j];
          po[(size_t)j * HWS] = fmaxf(v, 0.f);
        }
      }
    }
  }
}

extern "C" void kernel_launch(void* const* d_in, const int* in_sizes, int n_in,
                              void* d_out, int out_size, void* d_ws, size_t ws_size,
                              hipStream_t stream) {
  const float* x    = (const float*)d_in[0];
  const float* w    = (const float*)d_in[1];
  const float* bias = (const float*)d_in[2];
  float* out        = (float*)d_out;
  unsigned short* wb = (unsigned short*)d_ws;  // 1,179,648 B

  hipLaunchKernelGGL(wcvt_kernel, dim3(2304), dim3(256), 0, stream, w, wb);
  hipLaunchKernelGGL(conv_kernel, dim3(896), dim3(256), 0, stream,
                     x, (const unsigned char*)d_ws, bias, out);
}

// Round 7
// 169.014 us; speedup vs baseline: 2.8248x; 2.8248x over previous
//
#include <hip/hip_runtime.h>

// 3x3 SAME conv + bias + ReLU, N=32, Cin=Cout=256, H=W=56, fp32 in/out.
// v7 = v6 with xcvt phase-2 indexing fix (32 slots/row, not 64):
//  - x pre-transformed to NHWC bf16 (x_t[pix][ci]) once per launch.
//  - Both A (weights) and B (x_t) staged via async global_load_lds w=16,
//    XOR-swizzled via pre-swizzled per-lane GLOBAL source, linear LDS dest.
//  - Halo/out-of-image lanes read a zeroed 512B page (per-lane global addr).
//  - BM=128co x BN=128px, 4 waves, wave tile 64x64 (m4,n4, acc=64 regs).
//  - 2-phase dbuf, one barrier per K-step, 2 blocks/CU, tap-inner K order.

#define GLOBAL_AS __attribute__((address_space(1)))
#define LDS_AS __attribute__((address_space(3)))

typedef __attribute__((ext_vector_type(8))) short short8;
typedef __attribute__((ext_vector_type(4))) float f32x4;
typedef __attribute__((ext_vector_type(4))) unsigned int u32x4;

#define CIN   256
#define HWS   3136        // 56*56
#define PTOT  100352      // 32*3136
#define KTOT  2304        // CIN*9
#define WROWB 4608        // KTOT*2 bytes per weight row
#define ZPOFF 1179648     // 512B zero page
#define XTOFF 1310720     // x_t: PTOT*512 bytes
#define WSNEED (XTOFF + (size_t)PTOT * 512)

__device__ __forceinline__ unsigned short f2bf(float f) {
  unsigned u = __builtin_bit_cast(unsigned, f);
  return (unsigned short)((u + 0x7fffu + ((u >> 16) & 1u)) >> 16);  // RNE
}

// Weights OIHW fp32 -> bf16 [co][tap*256+ci]; also zero the zero-page.
__global__ void wcvt_kernel(const float* __restrict__ w, unsigned char* __restrict__ ws) {
  if (blockIdx.x == 0 && threadIdx.x < 128)
    ((unsigned*)(ws + ZPOFF))[threadIdx.x] = 0u;
  int o = blockIdx.x * 256 + threadIdx.x;
  int co = o / KTOT;
  int rr = o - co * KTOT;
  int tap = rr >> 8;
  int ci = rr & 255;
  ((unsigned short*)ws)[o] = f2bf(w[co * KTOT + ci * 9 + tap]);
}

// x NCHW fp32 -> x_t [pix_global][256ci] bf16 (NHWC), via LDS transpose.
__global__ __launch_bounds__(256) void xcvt_kernel(const float* __restrict__ x,
                                                   unsigned char* __restrict__ ws) {
  __shared__ float lt[64 * 257];
  const int pg0 = blockIdx.x * 64;       // 64-px tile, never crosses images
  const int n   = pg0 / HWS;
  const int pi0 = pg0 - n * HWS;
  const int t   = threadIdx.x;
  {
    const int px = t & 63;
    const int cg = t >> 6;               // 0..3 (wave-uniform)
    const float* xb = x + ((size_t)n * 256) * HWS + pi0 + px;
#pragma unroll 8
    for (int i = 0; i < 64; ++i) {
      const int c = i * 4 + cg;
      lt[px * 257 + c] = xb[(size_t)c * HWS];
    }
  }
  __syncthreads();
  {
    const int slot = t & 31;             // 16B slot = 8 channels (32 slots/row)
    const int pxw  = t >> 5;             // 0..7
    unsigned char* xt = ws + XTOFF;
#pragma unroll
    for (int i = 0; i < 8; ++i) {
      const int p = i * 8 + pxw;
      const float* r = &lt[p * 257 + slot * 8];
      u32x4 v;
#pragma unroll
      for (int j = 0; j < 4; ++j)
        v[j] = (unsigned)f2bf(r[2 * j]) | ((unsigned)f2bf(r[2 * j + 1]) << 16);
      *(u32x4*)(xt + (size_t)(pg0 + p) * 512 + slot * 16) = v;
    }
  }
}

__global__ __launch_bounds__(256, 2) void conv_kernel(
    const unsigned char* __restrict__ ws, const float* __restrict__ bias,
    float* __restrict__ out) {
  // LDS: buf{0,1} x (A 16KB + B 16KB)
  __shared__ __align__(16) unsigned char smem[65536];

  const unsigned char* wb = ws;
  const unsigned char* xt = ws + XTOFF;
  const unsigned char* zp = ws + ZPOFF;

  const int bid = blockIdx.x;
  const int sw  = (bid & 7) * 196 + (bid >> 3);  // XCD-chunked, bijective (1568=8*196)
  const int co0 = (sw & 1) * 128;
  const int p0  = (sw >> 1) * 128;               // global pixel base

  const int t    = threadIdx.x;
  const int lane = t & 63;
  const int wave = t >> 6;     // 0..3
  const int wm   = wave & 1;   // co 64-half
  const int wn   = wave >> 1;  // px 64-half
  const int rl   = lane & 15;
  const int kq   = lane >> 4;
  const int l7   = lane & 7;
  const int l8   = lane >> 3;

  // pre-swizzled k-offset within a 128B row (store & read use the same XOR)
  const unsigned chanoff = (unsigned)((l7 * 16) ^ ((l8 & 7) << 4));

  // ---- staging lane precompute (per op i=0..3, rows i*8+l8 per wave) ----
  const unsigned char* aG[4];
  long long bG[4];
  int hB[4], wB[4];
#pragma unroll
  for (int i = 0; i < 4; ++i) {
    const int row = wave * 32 + i * 8 + l8;       // 0..127
    aG[i] = wb + (size_t)(co0 + row) * WROWB + chanoff;
    const int pg = p0 + row;
    const int n  = pg / HWS;
    const int pi = pg - n * HWS;
    hB[i] = pi / 56;
    wB[i] = pi - hB[i] * 56;
    bG[i] = (long long)pg * 512 + (long long)chanoff;
  }

  f32x4 acc[4][4];
  const f32x4 zero4 = {0.f, 0.f, 0.f, 0.f};
#pragma unroll
  for (int mi = 0; mi < 4; ++mi)
#pragma unroll
    for (int ni = 0; ni < 4; ++ni) acc[mi][ni] = zero4;

  auto stage = [&](int s, int buf) {
    const int cq  = s / 9;
    const int tap = s - cq * 9;
    const int kh  = tap / 3;
    const int dh  = kh - 1;
    const int dw  = (tap - kh * 3) - 1;
    const int koffA = tap * 512 + cq * 128;
    unsigned char* lb = smem + buf * 32768;
#pragma unroll
    for (int i = 0; i < 4; ++i) {
      __builtin_amdgcn_global_load_lds(
          (const GLOBAL_AS unsigned int*)(aG[i] + koffA),
          (LDS_AS unsigned int*)(lb + (wave * 4 + i) * 1024), 16, 0, 0);
    }
    const long long doff = (long long)(dh * 56 + dw) * 512 + cq * 128;
#pragma unroll
    for (int i = 0; i < 4; ++i) {
      const int hh = hB[i] + dh;
      const int wwi = wB[i] + dw;
      const bool ok = ((unsigned)hh < 56u) && ((unsigned)wwi < 56u);
      const unsigned char* g = ok ? (xt + bG[i] + doff) : zp;
      __builtin_amdgcn_global_load_lds(
          (const GLOBAL_AS unsigned int*)g,
          (LDS_AS unsigned int*)(lb + 16384 + (wave * 4 + i) * 1024), 16, 0, 0);
    }
  };

  // compute-phase lane-constant offsets
  unsigned offA[2], offB[2];
#pragma unroll
  for (int ks = 0; ks < 2; ++ks) {
    const unsigned koff = (unsigned)((kq * 16 + ks * 64) ^ (l7 << 4));
    offA[ks] = (unsigned)((wm * 64 + rl) * 128) + koff;
    offB[ks] = (unsigned)((wn * 64 + rl) * 128) + koff;
  }

  auto compute = [&](int buf) {
    const unsigned char* bA = smem + buf * 32768;
    const unsigned char* bB = bA + 16384;
#pragma unroll
    for (int ks = 0; ks < 2; ++ks) {
      short8 a[4], b[4];
#pragma unroll
      for (int mi = 0; mi < 4; ++mi)
        a[mi] = *(const short8*)(bA + offA[ks] + mi * 2048);
#pragma unroll
      for (int ni = 0; ni < 4; ++ni)
        b[ni] = *(const short8*)(bB + offB[ks] + ni * 2048);
#pragma unroll
      for (int mi = 0; mi < 4; ++mi)
#pragma unroll
        for (int ni = 0; ni < 4; ++ni)
          acc[mi][ni] = __builtin_amdgcn_mfma_f32_16x16x32_bf16(
              a[mi], b[ni], acc[mi][ni], 0, 0, 0);
    }
  };

  // ---- 2-phase pipeline over 36 K-steps (tap-inner for x L2 reuse) ----
  stage(0, 0);
  __syncthreads();
  int buf = 0;
  for (int s = 0; s < 36; ++s) {
    if (s < 35) stage(s + 1, buf ^ 1);
    compute(buf);
    __syncthreads();
    buf ^= 1;
  }

  // ---- epilogue: bias + ReLU. C/D: col=lane&15, row=(lane>>4)*4+j ----
#pragma unroll
  for (int mi = 0; mi < 4; ++mi) {
    const int row = co0 + wm * 64 + mi * 16 + kq * 4;
    float br[4];
#pragma unroll
    for (int j = 0; j < 4; ++j) br[j] = bias[row + j];
#pragma unroll
    for (int ni = 0; ni < 4; ++ni) {
      const int pgb = p0 + wn * 64 + ni * 16;     // 16-span within one image
      const int n   = pgb / HWS;
      const int pib = pgb - n * HWS;
#pragma unroll
      for (int j = 0; j < 4; ++j) {
        float v = acc[mi][ni][j] + br[j];
        out[(size_t)(n * 256 + row + j) * HWS + pib + rl] = fmaxf(v, 0.f);
      }
    }
  }
}

// Correct-but-slow fallback if workspace is too small (not expected).
__global__ void naive_kernel(const float* __restrict__ x, const float* __restrict__ w,
                             const float* __restrict__ bias, float* __restrict__ out) {
  int idx = blockIdx.x * 256 + threadIdx.x;
  if (idx >= 32 * 256 * HWS) return;
  int n  = idx / (256 * HWS);
  int r  = idx - n * 256 * HWS;
  int co = r / HWS;
  int p  = r - co * HWS;
  int h = p / 56, ww = p - h * 56;
  float s = bias[co];
  const float* xb = x + (size_t)n * 256 * HWS;
  const float* wbp = w + (size_t)co * KTOT;
  for (int ci = 0; ci < 256; ++ci) {
    const float* xc = xb + (size_t)ci * HWS;
    const float* wc = wbp + ci * 9;
    for (int kh = 0; kh < 3; ++kh) {
      int hh = h + kh - 1;
      if ((unsigned)hh >= 56u) continue;
      for (int kw = 0; kw < 3; ++kw) {
        int w2 = ww + kw - 1;
        if ((unsigned)w2 >= 56u) continue;
        s += xc[hh * 56 + w2] * wc[kh * 3 + kw];
      }
    }
  }
  out[idx] = fmaxf(s, 0.f);
}

extern "C" void kernel_launch(void* const* d_in, const int* in_sizes, int n_in,
                              void* d_out, int out_size, void* d_ws, size_t ws_size,
                              hipStream_t stream) {
  const float* x    = (const float*)d_in[0];
  const float* w    = (const float*)d_in[1];
  const float* bias = (const float*)d_in[2];
  float* out        = (float*)d_out;

  if (ws_size < WSNEED) {
    hipLaunchKernelGGL(naive_kernel, dim3((32 * 256 * HWS + 255) / 256), dim3(256),
                       0, stream, x, w, bias, out);
    return;
  }
  unsigned char* ws = (unsigned char*)d_ws;
  hipLaunchKernelGGL(wcvt_kernel, dim3(2304), dim3(256), 0, stream, w, ws);
  hipLaunchKernelGGL(xcvt_kernel, dim3(PTOT / 64), dim3(256), 0, stream, x, ws);
  hipLaunchKernelGGL(conv_kernel, dim3(1568), dim3(256), 0, stream, ws, bias, out);
}